// Round 8
// baseline (13.949 us; speedup 1.0000x reference)
//
#include <hip/hip_runtime.h>

typedef _Float16 f16x8 __attribute__((ext_vector_type(8)));
typedef float    f32x4 __attribute__((ext_vector_type(4)));

#define S 512

static __device__ inline unsigned int pkrtz(float lo, float hi) {
    auto h = __builtin_amdgcn_cvt_pkrtz(lo, hi);   // __fp16 ext_vector(2)
    return __builtin_bit_cast(unsigned int, h);
}

// grid: 4 z * 128 a-quads = 512 blocks (2/CU), 4 waves, one a per wave.
// T[rm,j] = sum_b Bas[b,rm]*F[b,j] via mfma_f32_16x16x32_f16, K=512 in
// 2 chunks of 256 b.
//   A = Bas^T per-wave LDS [32 rm][256 b] fp16, XOR-swizzled, b64 writes
//   B = F^T   per-block LDS [16 j][512 b] fp16, XOR-swizzled, b64 writes
// Epilogue: T' fp16 [16 j][pad 40][32 rm] per wave; 2 b64 stores + 16 b128
// broadcast reads per lane; W contraction with v_fma_mix (fp16 x f32).
__global__ __launch_bounds__(256, 2)
void econv_mfma(const float* __restrict__ feat,   // [4][512][16]
                const float* __restrict__ geom,   // [4][512][3]
                const float* __restrict__ Wm,     // [32 rm][16 i][16 j]
                const int*   __restrict__ n_norm, // [1]
                float*       __restrict__ out)    // [4][512][16]
{
    __shared__ unsigned short FtU[16 * S];        // 16 KB  F^T fp16, swizzled
    __shared__ unsigned short BasU[4 * 32 * 256]; // 64 KB  per-wave Bas^T (reused as T')

    const int t = threadIdx.x;
    const int z = blockIdx.x >> 7;
    const int a0 = (blockIdx.x & 127) << 2;
    const int w = t >> 6;
    const int l = t & 63;
    const int a = a0 + w;

    const float* gz = geom + z * S * 3;
    const float* fz = feat + z * S * 16;

    // ---- F-staging loads: thread owns b-quad q = t&127, j-half jh = t>>7 ----
    const int fq  = t & 127;
    const int jh  = (t >> 7) & 1;
    const float* fp = fz + fq * 64 + jh * 8;     // row 4*fq, j = jh*8..
    f32x4 fr0a = *(const f32x4*)(fp +   0), fr0b = *(const f32x4*)(fp +   4);
    f32x4 fr1a = *(const f32x4*)(fp +  16), fr1b = *(const f32x4*)(fp +  20);
    f32x4 fr2a = *(const f32x4*)(fp +  32), fr2b = *(const f32x4*)(fp +  36);
    f32x4 fr3a = *(const f32x4*)(fp +  48), fr3b = *(const f32x4*)(fp +  52);

    // ---- geometry prefetch for both chunks (4 b's per lane each) ----
    f32x4 gq00 = *(const f32x4*)(gz + 12 * l);
    f32x4 gq01 = *(const f32x4*)(gz + 12 * l + 4);
    f32x4 gq02 = *(const f32x4*)(gz + 12 * l + 8);
    f32x4 gq10 = *(const f32x4*)(gz + 768 + 12 * l);
    f32x4 gq11 = *(const f32x4*)(gz + 768 + 12 * l + 4);
    f32x4 gq12 = *(const f32x4*)(gz + 768 + 12 * l + 8);

    const float gax = gz[3 * a], gay = gz[3 * a + 1], gaz = gz[3 * a + 2];

    // ---- write F^T fp16 swizzled: b-quad as uint2 at row j, byte (8q)^((j&7)<<4) ----
    {
        char* FtB = (char*)FtU;
        const int wb = 8 * fq;
#define STJ(JJ, RA, RB)  { \
        const int j = jh * 8 + JJ; \
        uint2 p; p.x = pkrtz(fr0##RA[JJ & 3], fr1##RA[JJ & 3]); \
                 p.y = pkrtz(fr2##RA[JJ & 3], fr3##RA[JJ & 3]); \
        *(uint2*)(FtB + j * 1024 + (wb ^ ((j & 7) << 4))) = p; }
        // j = jh*8 + 0..3 come from the 'a' regs, 4..7 from the 'b' regs
        { const int j = jh*8+0; uint2 p; p.x=pkrtz(fr0a[0],fr1a[0]); p.y=pkrtz(fr2a[0],fr3a[0]); *(uint2*)(FtB + j*1024 + (wb ^ ((j&7)<<4))) = p; }
        { const int j = jh*8+1; uint2 p; p.x=pkrtz(fr0a[1],fr1a[1]); p.y=pkrtz(fr2a[1],fr3a[1]); *(uint2*)(FtB + j*1024 + (wb ^ ((j&7)<<4))) = p; }
        { const int j = jh*8+2; uint2 p; p.x=pkrtz(fr0a[2],fr1a[2]); p.y=pkrtz(fr2a[2],fr3a[2]); *(uint2*)(FtB + j*1024 + (wb ^ ((j&7)<<4))) = p; }
        { const int j = jh*8+3; uint2 p; p.x=pkrtz(fr0a[3],fr1a[3]); p.y=pkrtz(fr2a[3],fr3a[3]); *(uint2*)(FtB + j*1024 + (wb ^ ((j&7)<<4))) = p; }
        { const int j = jh*8+4; uint2 p; p.x=pkrtz(fr0b[0],fr1b[0]); p.y=pkrtz(fr2b[0],fr3b[0]); *(uint2*)(FtB + j*1024 + (wb ^ ((j&7)<<4))) = p; }
        { const int j = jh*8+5; uint2 p; p.x=pkrtz(fr0b[1],fr1b[1]); p.y=pkrtz(fr2b[1],fr3b[1]); *(uint2*)(FtB + j*1024 + (wb ^ ((j&7)<<4))) = p; }
        { const int j = jh*8+6; uint2 p; p.x=pkrtz(fr0b[2],fr1b[2]); p.y=pkrtz(fr2b[2],fr3b[2]); *(uint2*)(FtB + j*1024 + (wb ^ ((j&7)<<4))) = p; }
        { const int j = jh*8+7; uint2 p; p.x=pkrtz(fr0b[3],fr1b[3]); p.y=pkrtz(fr2b[3],fr3b[3]); *(uint2*)(FtB + j*1024 + (wb ^ ((j&7)<<4))) = p; }
#undef STJ
    }
    __syncthreads();   // only barrier; waves independent afterwards

    char* BasB = (char*)BasU + w * 16384;   // this wave's 16 KB slice
    char* FtB  = (char*)FtU;

    const int mrow = l & 15;            // rm row (tile0) == F^T row j == out i
    const int g    = l >> 4;
    const int rkey = (mrow & 7) << 4;   // read swizzle key (same for mrow+16)
    const int wbb  = 8 * l;             // write byte base within 512B Bas row

    f32x4 acc0 = {0.f, 0.f, 0.f, 0.f};
    f32x4 acc1 = {0.f, 0.f, 0.f, 0.f};

#pragma unroll
    for (int c = 0; c < 2; ++c) {
        f32x4 g0 = c ? gq10 : gq00;   // x0 y0 z0 x1
        f32x4 g1 = c ? gq11 : gq01;   // y1 z1 x2 y2
        f32x4 g2 = c ? gq12 : gq02;   // z2 x3 y3 z3

        float dx[4] = {g0[0] - gax, g0[3] - gax, g1[2] - gax, g2[1] - gax};
        float dy[4] = {g0[1] - gay, g1[0] - gay, g1[3] - gay, g2[2] - gay};
        float dz[4] = {g0[2] - gaz, g1[1] - gaz, g2[0] - gaz, g2[3] - gaz};

        float dsq[4], ux[4], uy[4], uz[4];
#pragma unroll
        for (int b = 0; b < 4; ++b) {
            float ss  = fmaf(dx[b], dx[b], fmaf(dy[b], dy[b], fmaf(dz[b], dz[b], 1e-12f)));
            float inv = rsqrtf(ss);
            dsq[b] = (ss * inv) * 2.82842712f;   // sqrt(8) * d
            ux[b] = dx[b] * inv; uy[b] = dy[b] * inv; uz[b] = dz[b] * inv;
        }

        // ---- basis rows: rad_r = exp(-(sqrt8*d - sqrt8*c_r)^2), b64 writes ----
#pragma unroll
        for (int r = 0; r < 8; ++r) {
            const float cs = (float)r * 1.21218305f;   // (3/7)*sqrt(8)*r
            float rd[4];
#pragma unroll
            for (int b = 0; b < 4; ++b) {
                float e = dsq[b] - cs;
                rd[b] = __expf(-(e * e));
            }
            uint2 p;
            p.x = pkrtz(rd[0], rd[1]);           p.y = pkrtz(rd[2], rd[3]);
            *(uint2*)(BasB + (4*r+0) * 512 + (wbb ^ (((4*r+0) & 7) << 4))) = p;
            p.x = pkrtz(rd[0]*ux[0], rd[1]*ux[1]); p.y = pkrtz(rd[2]*ux[2], rd[3]*ux[3]);
            *(uint2*)(BasB + (4*r+1) * 512 + (wbb ^ (((4*r+1) & 7) << 4))) = p;
            p.x = pkrtz(rd[0]*uy[0], rd[1]*uy[1]); p.y = pkrtz(rd[2]*uy[2], rd[3]*uy[3]);
            *(uint2*)(BasB + (4*r+2) * 512 + (wbb ^ (((4*r+2) & 7) << 4))) = p;
            p.x = pkrtz(rd[0]*uz[0], rd[1]*uz[1]); p.y = pkrtz(rd[2]*uz[2], rd[3]*uz[3]);
            *(uint2*)(BasB + (4*r+3) * 512 + (wbb ^ (((4*r+3) & 7) << 4))) = p;
        }

        // ---- 8 k-steps of MFMA over this 256-b chunk ----
#pragma unroll
        for (int ks = 0; ks < 8; ++ks) {
            const int col = 64 * ks + 16 * g;
            f16x8 A0 = *(f16x8*)(BasB + mrow * 512        + (col ^ rkey));
            f16x8 A1 = *(f16x8*)(BasB + (mrow + 16) * 512 + (col ^ rkey));
            f16x8 Bf = *(f16x8*)(FtB + mrow * 1024 + ((c * 512 + col) ^ rkey));
            acc0 = __builtin_amdgcn_mfma_f32_16x16x32_f16(A0, Bf, acc0, 0, 0, 0);
            acc1 = __builtin_amdgcn_mfma_f32_16x16x32_f16(A1, Bf, acc1, 0, 0, 0);
        }
    }

    // ---- epilogue (wave-local, no barrier): T' fp16 [16 j][pad 80B][32 rm] ----
    {
        char* Tp = BasB;    // 16 rows x 80 B = 1280 B
        uint2 p0, p1;
        p0.x = pkrtz(acc0[0], acc0[1]); p0.y = pkrtz(acc0[2], acc0[3]);
        p1.x = pkrtz(acc1[0], acc1[1]); p1.y = pkrtz(acc1[2], acc1[3]);
        // acc0[q] = T[rm=4g+q][j=mrow] -> T'[j=mrow][rm=4g+q]
        *(uint2*)(Tp + mrow * 80 + 8 * g)      = p0;
        *(uint2*)(Tp + mrow * 80 + 32 + 8 * g) = p1;
    }

    // lane (i = mrow, j-quad = g): o = sum_rm sum_{j in quad} T'[j][rm] * W[rm][i][j]
    float o = 0.f;
    {
        const char* Tp = BasB;
        const float* Wp = Wm + mrow * 16 + 4 * g;   // + rm*256 per row
#pragma unroll
        for (int rm8 = 0; rm8 < 4; ++rm8) {
            f16x8 t0 = *(const f16x8*)(Tp + (4 * g + 0) * 80 + rm8 * 16);
            f16x8 t1 = *(const f16x8*)(Tp + (4 * g + 1) * 80 + rm8 * 16);
            f16x8 t2 = *(const f16x8*)(Tp + (4 * g + 2) * 80 + rm8 * 16);
            f16x8 t3 = *(const f16x8*)(Tp + (4 * g + 3) * 80 + rm8 * 16);
#pragma unroll
            for (int e = 0; e < 8; ++e) {
                f32x4 wv = *(const f32x4*)(Wp + (rm8 * 8 + e) * 256);
                o = fmaf((float)t0[e], wv[0], o);
                o = fmaf((float)t1[e], wv[1], o);
                o = fmaf((float)t2[e], wv[2], o);
                o = fmaf((float)t3[e], wv[3], o);
            }
        }
    }
    o += __shfl_xor(o, 16);
    o += __shfl_xor(o, 32);
    if (l < 16) {
        const float scale = rsqrtf((float)n_norm[0]);   // 1/sqrt(512)
        out[(z * S + a) * 16 + mrow] = o * scale;
    }
}

extern "C" void kernel_launch(void* const* d_in, const int* in_sizes, int n_in,
                              void* d_out, int out_size, void* d_ws, size_t ws_size,
                              hipStream_t stream) {
    const float* feat   = (const float*)d_in[0];
    const float* geomp  = (const float*)d_in[1];
    const float* Wm     = (const float*)d_in[2];
    const int*   n_norm = (const int*)d_in[3];
    float* outp = (float*)d_out;

    econv_mfma<<<dim3(512), dim3(256), 0, stream>>>(feat, geomp, Wm, n_norm, outp);
}